// Round 1
// baseline (155.923 us; speedup 1.0000x reference)
//
#include <hip/hip_runtime.h>

// HeuristicGNN: collapses to
//   edges[i][j] = relu(E_w[i] + E_w[32+j] + E_b)           (batch-independent)
//   he[n,i]     = sum_j edges[i,j] * mask[n,i,j]
//   h[n]        = mean_i relu(N_w[i] + N_b + N_w[32]*he[n,i])
//   pred[n]     = O2w * relu(O1w0*h_s + O1w1*h_g + O1b) + O2b
// Memory-bound: 512 MiB of mask reads, ~85 us roofline @ 6.3 TB/s.

static __device__ __forceinline__ float frelu(float x) { return x > 0.f ? x : 0.f; }

__global__ __launch_bounds__(256) void gnn_kernel(
    const float* __restrict__ smask,
    const float* __restrict__ gmask,
    const float* __restrict__ E_w,
    const float* __restrict__ E_b,
    const float* __restrict__ N_w,
    const float* __restrict__ N_b,
    const float* __restrict__ O1_w,
    const float* __restrict__ O1_b,
    const float* __restrict__ O2_w,
    const float* __restrict__ O2_b,
    float* __restrict__ out,
    int N)
{
    const int lane = threadIdx.x & 63;
    const int i    = lane >> 1;          // object row 0..31 (two lanes per i)
    const int j0   = (lane & 1) << 4;    // this lane covers j0..j0+15

    // Per-lane constants (batch-independent) — 16 edge values in registers.
    const float eb  = E_b[0];
    const float ewi = E_w[i];
    float el[16];
#pragma unroll
    for (int k = 0; k < 16; ++k)
        el[k] = frelu(ewi + E_w[32 + j0 + k] + eb);

    const float c0   = N_w[i] + N_b[0];  // one-hot node feature contribution
    const float a    = N_w[32];          // weight on he
    const float o1w0 = O1_w[0], o1w1 = O1_w[1], o1b = O1_b[0];
    const float o2w  = O2_w[0], o2b = O2_b[0];

    const int wave = blockIdx.x * (blockDim.x >> 6) + (threadIdx.x >> 6);
    const int nwav = gridDim.x * (blockDim.x >> 6);

    for (int n = wave; n < N; n += nwav) {
        const size_t base = (size_t)n * 1024 + (size_t)lane * 16;
        const float4* sp = (const float4*)(smask + base);
        const float4* gp = (const float4*)(gmask + base);
        float4 s[4], g[4];
#pragma unroll
        for (int q = 0; q < 4; ++q) s[q] = sp[q];
#pragma unroll
        for (int q = 0; q < 4; ++q) g[q] = gp[q];

        float ps = 0.f, pg = 0.f;
#pragma unroll
        for (int q = 0; q < 4; ++q) {
            ps += s[q].x * el[4*q+0] + s[q].y * el[4*q+1]
                + s[q].z * el[4*q+2] + s[q].w * el[4*q+3];
            pg += g[q].x * el[4*q+0] + g[q].y * el[4*q+1]
                + g[q].z * el[4*q+2] + g[q].w * el[4*q+3];
        }

        // Merge the two half-rows of each i: lanes 2i and 2i+1 both get he[i].
        float hes = ps + __shfl_xor(ps, 1);
        float heg = pg + __shfl_xor(pg, 1);

        float hns = frelu(c0 + a * hes);
        float hng = frelu(c0 + a * heg);

        // Butterfly sum over remaining lanes: total = 2 * sum_i hn[i].
#pragma unroll
        for (int m = 2; m <= 32; m <<= 1) {
            hns += __shfl_xor(hns, m);
            hng += __shfl_xor(hng, m);
        }

        if (lane == 0) {
            float hs = hns * (1.f / 64.f);   // = mean over 32 i's
            float hg = hng * (1.f / 64.f);
            float t  = frelu(o1w0 * hs + o1w1 * hg + o1b);
            out[n] = o2w * t + o2b;
        }
    }
}

extern "C" void kernel_launch(void* const* d_in, const int* in_sizes, int n_in,
                              void* d_out, int out_size, void* d_ws, size_t ws_size,
                              hipStream_t stream) {
    const float* smask = (const float*)d_in[0];
    const float* gmask = (const float*)d_in[1];
    const float* E_w   = (const float*)d_in[2];
    const float* E_b   = (const float*)d_in[3];
    const float* N_w   = (const float*)d_in[4];
    const float* N_b   = (const float*)d_in[5];
    const float* O1_w  = (const float*)d_in[6];
    const float* O1_b  = (const float*)d_in[7];
    const float* O2_w  = (const float*)d_in[8];
    const float* O2_b  = (const float*)d_in[9];
    float* out = (float*)d_out;

    const int N = in_sizes[0] / 1024;  // (N, 32, 32) masks

    int blocks = 2048;                 // 8192 waves, ~8 rows each
    const int wavesPerBlock = 4;
    if (blocks * wavesPerBlock > N) blocks = (N + wavesPerBlock - 1) / wavesPerBlock;

    gnn_kernel<<<blocks, 256, 0, stream>>>(
        smask, gmask, E_w, E_b, N_w, N_b, O1_w, O1_b, O2_w, O2_b, out, N);
}

// Round 2
// 100.756 us; speedup vs baseline: 1.5475x; 1.5475x over previous
//
#include <hip/hip_runtime.h>

// HeuristicGNN closed form:
//   edges[i][j] = relu(E_w[i] + E_w[32+j] + E_b)           (batch-independent)
//   he[n,i]     = sum_j edges[i,j] * mask[n,i,j]
//   h[n]        = mean_i relu(N_w[i] + N_b + N_w[32]*he[n,i])
//   pred[n]     = O2w * relu(O1w0*h_s + O1w1*h_g + O1b) + O2b
//
// R1: lane layout changed so every global_load_dwordx4 is wave-contiguous
// (64 lanes x 16 B = 1 KiB per instruction, 8 cache lines) instead of
// lane-strided (32 lines/instr) — R0 hit only 2.8 TB/s from address
// divergence. Chunk q covers rows i = q*8..q*8+7; lane l owns
// i = q*8 + (l>>3), j = 4*(l&7)..+3.

static __device__ __forceinline__ float frelu(float x) { return x > 0.f ? x : 0.f; }

__global__ __launch_bounds__(256) void gnn_kernel(
    const float* __restrict__ smask,
    const float* __restrict__ gmask,
    const float* __restrict__ E_w,
    const float* __restrict__ E_b,
    const float* __restrict__ N_w,
    const float* __restrict__ N_b,
    const float* __restrict__ O1_w,
    const float* __restrict__ O1_b,
    const float* __restrict__ O2_w,
    const float* __restrict__ O2_b,
    float* __restrict__ out,
    int N)
{
    const int lane = threadIdx.x & 63;
    const int grp  = lane >> 3;          // 0..7: row within each 8-row chunk
    const int jb   = (lane & 7) << 2;    // 0,4,...,28: first of 4 cols

    // Batch-independent per-lane constants: 16 edge weights + 4 node consts.
    const float eb = E_b[0];
    const float nb = N_b[0];
    const float a  = N_w[32];
    float el[4][4], c0[4];
#pragma unroll
    for (int q = 0; q < 4; ++q) {
        const int iq = q * 8 + grp;
        const float ewi = E_w[iq];
#pragma unroll
        for (int k = 0; k < 4; ++k)
            el[q][k] = frelu(ewi + E_w[32 + jb + k] + eb);
        c0[q] = N_w[iq] + nb;
    }
    const float o1w0 = O1_w[0], o1w1 = O1_w[1], o1b = O1_b[0];
    const float o2w  = O2_w[0], o2b = O2_b[0];

    const int wave = blockIdx.x * (blockDim.x >> 6) + (threadIdx.x >> 6);
    const int nwav = gridDim.x * (blockDim.x >> 6);

    for (int n = wave; n < N; n += nwav) {
        const float4* sp = (const float4*)(smask + (size_t)n * 1024);
        const float4* gp = (const float4*)(gmask + (size_t)n * 1024);
        // 8 wave-contiguous 1 KiB loads (4 per mask).
        float4 s0 = sp[lane], s1 = sp[64 + lane], s2 = sp[128 + lane], s3 = sp[192 + lane];
        float4 g0 = gp[lane], g1 = gp[64 + lane], g2 = gp[128 + lane], g3 = gp[192 + lane];

        float ps[4], pg[4];
        ps[0] = s0.x*el[0][0] + s0.y*el[0][1] + s0.z*el[0][2] + s0.w*el[0][3];
        ps[1] = s1.x*el[1][0] + s1.y*el[1][1] + s1.z*el[1][2] + s1.w*el[1][3];
        ps[2] = s2.x*el[2][0] + s2.y*el[2][1] + s2.z*el[2][2] + s2.w*el[2][3];
        ps[3] = s3.x*el[3][0] + s3.y*el[3][1] + s3.z*el[3][2] + s3.w*el[3][3];
        pg[0] = g0.x*el[0][0] + g0.y*el[0][1] + g0.z*el[0][2] + g0.w*el[0][3];
        pg[1] = g1.x*el[1][0] + g1.y*el[1][1] + g1.z*el[1][2] + g1.w*el[1][3];
        pg[2] = g2.x*el[2][0] + g2.y*el[2][1] + g2.z*el[2][2] + g2.w*el[2][3];
        pg[3] = g3.x*el[3][0] + g3.y*el[3][1] + g3.z*el[3][2] + g3.w*el[3][3];

        // he over j: butterfly within each 8-lane group (8 independent chains).
#pragma unroll
        for (int m = 1; m <= 4; m <<= 1) {
#pragma unroll
            for (int q = 0; q < 4; ++q) {
                ps[q] += __shfl_xor(ps[q], m);
                pg[q] += __shfl_xor(pg[q], m);
            }
        }

        // Node MLP + sum over this lane's 4 rows.
        float ts = 0.f, tg = 0.f;
#pragma unroll
        for (int q = 0; q < 4; ++q) {
            ts += frelu(c0[q] + a * ps[q]);
            tg += frelu(c0[q] + a * pg[q]);
        }

        // Sum across the 8 groups (each row counted 8x).
#pragma unroll
        for (int m = 8; m <= 32; m <<= 1) {
            ts += __shfl_xor(ts, m);
            tg += __shfl_xor(tg, m);
        }

        if (lane == 0) {
            const float hs = ts * (1.f / 256.f);  // /8 replication /32 mean
            const float hg = tg * (1.f / 256.f);
            const float t  = frelu(o1w0 * hs + o1w1 * hg + o1b);
            out[n] = o2w * t + o2b;
        }
    }
}

extern "C" void kernel_launch(void* const* d_in, const int* in_sizes, int n_in,
                              void* d_out, int out_size, void* d_ws, size_t ws_size,
                              hipStream_t stream) {
    const float* smask = (const float*)d_in[0];
    const float* gmask = (const float*)d_in[1];
    const float* E_w   = (const float*)d_in[2];
    const float* E_b   = (const float*)d_in[3];
    const float* N_w   = (const float*)d_in[4];
    const float* N_b   = (const float*)d_in[5];
    const float* O1_w  = (const float*)d_in[6];
    const float* O1_b  = (const float*)d_in[7];
    const float* O2_w  = (const float*)d_in[8];
    const float* O2_b  = (const float*)d_in[9];
    float* out = (float*)d_out;

    const int N = in_sizes[0] / 1024;  // (N, 32, 32) masks

    int blocks = 2048;                 // 8192 waves, ~8 rows each
    const int wavesPerBlock = 4;
    if (blocks * wavesPerBlock > N) blocks = (N + wavesPerBlock - 1) / wavesPerBlock;

    gnn_kernel<<<blocks, 256, 0, stream>>>(
        smask, gmask, E_w, E_b, N_w, N_b, O1_w, O1_b, O2_w, O2_b, out, N);
}

// Round 4
// 88.063 us; speedup vs baseline: 1.7706x; 1.1441x over previous
//
#include <hip/hip_runtime.h>

// HeuristicGNN closed form:
//   edges[i][j] = relu(E_w[i] + E_w[32+j] + E_b)           (batch-independent)
//   he[n,i]     = sum_j edges[i,j] * mask[n,i,j]
//   h[n]        = mean_i relu(N_w[i] + N_b + N_w[32]*he[n,i])
//   pred[n]     = O2w * relu(O1w0*h_s + O1w1*h_g + O1b) + O2b
//
// R1: wave-contiguous float4 loads (1 KiB/instr): 182 -> 101 us, 5.3 TB/s.
// R2/R3: n-loop unrolled x2 (16 loads in flight) + nontemporal loads via
//        clang ext_vector type (HIP_vector_type rejected by the builtin).

typedef float f4 __attribute__((ext_vector_type(4)));

static __device__ __forceinline__ float frelu(float x) { return x > 0.f ? x : 0.f; }

__global__ __launch_bounds__(256) void gnn_kernel(
    const float* __restrict__ smask,
    const float* __restrict__ gmask,
    const float* __restrict__ E_w,
    const float* __restrict__ E_b,
    const float* __restrict__ N_w,
    const float* __restrict__ N_b,
    const float* __restrict__ O1_w,
    const float* __restrict__ O1_b,
    const float* __restrict__ O2_w,
    const float* __restrict__ O2_b,
    float* __restrict__ out,
    int N)
{
    const int lane = threadIdx.x & 63;
    const int grp  = lane >> 3;          // 0..7: row within each 8-row chunk
    const int jb   = (lane & 7) << 2;    // 0,4,...,28: first of 4 cols

    // Batch-independent per-lane constants: 16 edge weights + 4 node consts.
    const float eb = E_b[0];
    const float nb = N_b[0];
    const float a  = N_w[32];
    float el[4][4], c0[4];
#pragma unroll
    for (int q = 0; q < 4; ++q) {
        const int iq = q * 8 + grp;
        const float ewi = E_w[iq];
#pragma unroll
        for (int k = 0; k < 4; ++k)
            el[q][k] = frelu(ewi + E_w[32 + jb + k] + eb);
        c0[q] = N_w[iq] + nb;
    }
    const float o1w0 = O1_w[0], o1w1 = O1_w[1], o1b = O1_b[0];
    const float o2w  = O2_w[0], o2b = O2_b[0];

    const int wave = blockIdx.x * (blockDim.x >> 6) + (threadIdx.x >> 6);
    const int nwav = gridDim.x * (blockDim.x >> 6);

    for (int n = wave; n < N; n += 2 * nwav) {
        const int n2 = n + nwav;
        const bool has2 = (n2 < N);      // wave-uniform

        const f4* spA = (const f4*)(smask + (size_t)n * 1024);
        const f4* gpA = (const f4*)(gmask + (size_t)n * 1024);
        const f4* spB = (const f4*)(smask + (size_t)(has2 ? n2 : n) * 1024);
        const f4* gpB = (const f4*)(gmask + (size_t)(has2 ? n2 : n) * 1024);

        // 16 wave-contiguous 1 KiB nontemporal loads, issued back-to-back.
        f4 sA[4], gA[4], sB[4], gB[4];
#pragma unroll
        for (int q = 0; q < 4; ++q) sA[q] = __builtin_nontemporal_load(&spA[q * 64 + lane]);
#pragma unroll
        for (int q = 0; q < 4; ++q) gA[q] = __builtin_nontemporal_load(&gpA[q * 64 + lane]);
#pragma unroll
        for (int q = 0; q < 4; ++q) sB[q] = __builtin_nontemporal_load(&spB[q * 64 + lane]);
#pragma unroll
        for (int q = 0; q < 4; ++q) gB[q] = __builtin_nontemporal_load(&gpB[q * 64 + lane]);

        float psA[4], pgA[4], psB[4], pgB[4];
#pragma unroll
        for (int q = 0; q < 4; ++q) {
            psA[q] = sA[q].x*el[q][0] + sA[q].y*el[q][1] + sA[q].z*el[q][2] + sA[q].w*el[q][3];
            pgA[q] = gA[q].x*el[q][0] + gA[q].y*el[q][1] + gA[q].z*el[q][2] + gA[q].w*el[q][3];
            psB[q] = sB[q].x*el[q][0] + sB[q].y*el[q][1] + sB[q].z*el[q][2] + sB[q].w*el[q][3];
            pgB[q] = gB[q].x*el[q][0] + gB[q].y*el[q][1] + gB[q].z*el[q][2] + gB[q].w*el[q][3];
        }

        // he over j: butterfly within each 8-lane group.
#pragma unroll
        for (int m = 1; m <= 4; m <<= 1) {
#pragma unroll
            for (int q = 0; q < 4; ++q) {
                psA[q] += __shfl_xor(psA[q], m);
                pgA[q] += __shfl_xor(pgA[q], m);
                psB[q] += __shfl_xor(psB[q], m);
                pgB[q] += __shfl_xor(pgB[q], m);
            }
        }

        // Node MLP + sum over this lane's 4 rows.
        float tsA = 0.f, tgA = 0.f, tsB = 0.f, tgB = 0.f;
#pragma unroll
        for (int q = 0; q < 4; ++q) {
            tsA += frelu(c0[q] + a * psA[q]);
            tgA += frelu(c0[q] + a * pgA[q]);
            tsB += frelu(c0[q] + a * psB[q]);
            tgB += frelu(c0[q] + a * pgB[q]);
        }

        // Sum across the 8 groups (each row counted 8x).
#pragma unroll
        for (int m = 8; m <= 32; m <<= 1) {
            tsA += __shfl_xor(tsA, m);
            tgA += __shfl_xor(tgA, m);
            tsB += __shfl_xor(tsB, m);
            tgB += __shfl_xor(tgB, m);
        }

        if (lane == 0) {
            {
                const float hs = tsA * (1.f / 256.f);
                const float hg = tgA * (1.f / 256.f);
                const float t  = frelu(o1w0 * hs + o1w1 * hg + o1b);
                out[n] = o2w * t + o2b;
            }
            if (has2) {
                const float hs = tsB * (1.f / 256.f);
                const float hg = tgB * (1.f / 256.f);
                const float t  = frelu(o1w0 * hs + o1w1 * hg + o1b);
                out[n2] = o2w * t + o2b;
            }
        }
    }
}

extern "C" void kernel_launch(void* const* d_in, const int* in_sizes, int n_in,
                              void* d_out, int out_size, void* d_ws, size_t ws_size,
                              hipStream_t stream) {
    const float* smask = (const float*)d_in[0];
    const float* gmask = (const float*)d_in[1];
    const float* E_w   = (const float*)d_in[2];
    const float* E_b   = (const float*)d_in[3];
    const float* N_w   = (const float*)d_in[4];
    const float* N_b   = (const float*)d_in[5];
    const float* O1_w  = (const float*)d_in[6];
    const float* O1_b  = (const float*)d_in[7];
    const float* O2_w  = (const float*)d_in[8];
    const float* O2_b  = (const float*)d_in[9];
    float* out = (float*)d_out;

    const int N = in_sizes[0] / 1024;  // (N, 32, 32) masks

    int blocks = 2048;                 // 8192 waves, 8 rows each (4 iters unrolled x2)
    const int wavesPerBlock = 4;
    if (blocks * wavesPerBlock > N) blocks = (N + wavesPerBlock - 1) / wavesPerBlock;

    gnn_kernel<<<blocks, 256, 0, stream>>>(
        smask, gmask, E_w, E_b, N_w, N_b, O1_w, O1_b, O2_w, O2_b, out, N);
}